// Round 4
// baseline (156.697 us; speedup 1.0000x reference)
//
#include <hip/hip_runtime.h>
#include <stdint.h>
#include <stddef.h>

// Problem: X=2048, Y=256, F=128, H=8, NF=32, O=H*NF=256.
// Inputs/outputs are FLOAT32 on device (npz sizes prove it); mask int32.
//
// Design (round 4): round-3 structure, f32 I/O, split-bf16 MFMA:
//  - one 512-thread block per 8 x's; wave w owns output rows [32w, 32w+32)
//  - A = leaky_relu(xy) split into bf16 hi+lo in registers; main GEMM 2-pass
//    (Ah*W1h + Al*W1h); logits 3-pass (Ah*W2h + Al*W2h + Ah*W2l)
//  - W1/W2 gathered once per block into fragment-ordered LDS (plain stores)
//  - all cross-wave sync via __syncthreads() only

typedef __attribute__((ext_vector_type(8))) short bf16x8;   // 8 bf16 = 4 VGPRs
typedef __attribute__((ext_vector_type(8))) float f32x8;
typedef __attribute__((ext_vector_type(4))) float f32x4;

#define XPB 8
#define NBLK 256

// dynamic LDS layout (bytes)
#define OFF_W1H  0u        // 65536: W1 hi fragments [nt*4+kk][lane][8] bf16
#define OFF_W2H  65536u    // 4096 : W2 hi fragments [kk][lane][8] bf16 (cols 8..15 = 0)
#define OFF_W2L  69632u    // 4096 : W2 lo fragments
#define OFF_COEF 73728u    // 8192 : float[8][256] logits -> coefs (head-major)
#define OFF_OUTP 81920u    // 8192 : float[8][256] per-wave output partials
#define OFF_B1   90112u    // 1024 : float[256]
#define OFF_G    91136u    // 1024
#define OFF_BT   92160u    // 1024
#define OFF_B2   93184u    // 64   : float[16]
#define LDS_BYTES 93248u

__device__ __forceinline__ float bf2f(uint32_t u){
  union { uint32_t i; float f; } v; v.i = u << 16; return v.f;
}
__device__ __forceinline__ uint16_t f2bf(float f){
  union { float f; uint32_t i; } v; v.f = f;
  uint32_t i = v.i;
  return (uint16_t)((i + 0x7FFFu + ((i >> 16) & 1u)) >> 16);  // RN-even
}

__device__ __forceinline__ f32x4 mfma16(bf16x8 a, bf16x8 b, f32x4 c){
  return __builtin_amdgcn_mfma_f32_16x16x32_bf16(a, b, c, 0, 0, 0);
}

__global__ __launch_bounds__(512, 2) void attn_main(
    const float* __restrict__ xy, const int* __restrict__ mask,
    const float* __restrict__ W1g, const float* __restrict__ b1g,
    const float* __restrict__ gammag, const float* __restrict__ betag,
    const float* __restrict__ W2g, const float* __restrict__ b2g,
    float* __restrict__ out)
{
  extern __shared__ char smem[];
  const int tid = threadIdx.x;
  const int l  = tid & 63;
  const int w  = tid >> 6;     // wave 0..7
  const int lg = l >> 4;       // lane group 0..3
  const int lc = l & 15;

  uint16_t* w1h = (uint16_t*)(smem + OFF_W1H);
  uint16_t* w2h = (uint16_t*)(smem + OFF_W2H);
  uint16_t* w2l = (uint16_t*)(smem + OFF_W2L);
  float* coefT = (float*)(smem + OFF_COEF);
  float* outp  = (float*)(smem + OFF_OUTP);
  float* ldsB1 = (float*)(smem + OFF_B1);
  float* ldsG  = (float*)(smem + OFF_G);
  float* ldsBt = (float*)(smem + OFF_BT);
  float* ldsB2 = (float*)(smem + OFF_B2);

  if (tid < 256){
    ldsB1[tid] = b1g[tid];
    ldsG[tid]  = gammag[tid];
    ldsBt[tid] = betag[tid];
  }
  if (tid < 16) ldsB2[tid] = (tid < 8) ? b2g[tid] : 0.f;

  // ---- gather W1 (f32) -> bf16-hi fragment order:
  //      idx=((nt*4+kk)*64+l)*8+j, value=W1[f][o], f=kk*32+(l>>4)*8+j, o=nt*16+(l&15)
  #pragma unroll
  for (int i = 0; i < 8; ++i){
    int base = i * 4096 + tid * 8;
    int bl  = (base >> 3) & 63;
    int bkk = (base >> 9) & 3;
    int bnt = base >> 11;
    int o   = bnt * 16 + (bl & 15);
    int f0  = bkk * 32 + ((bl >> 4) << 3);
    bf16x8 vh;
    #pragma unroll
    for (int j = 0; j < 8; ++j) vh[j] = (short)f2bf(W1g[(size_t)(f0 + j) * 256 + o]);
    *(bf16x8*)(w1h + base) = vh;
  }
  // ---- gather W2 hi+lo (pad cols 8..15 with zero) ----
  if (tid < 256){
    int base = tid * 8;
    int bl  = (base >> 3) & 63;
    int bkk = base >> 9;
    int h   = bl & 15;
    int f0  = bkk * 32 + ((bl >> 4) << 3);
    bf16x8 vh, vl;
    #pragma unroll
    for (int j = 0; j < 8; ++j){
      float v = (h < 8) ? W2g[(size_t)(f0 + j) * 8 + h] : 0.f;
      uint16_t hi = f2bf(v);
      float    r  = v - bf2f(hi);
      vh[j] = (short)hi;
      vl[j] = (short)f2bf(r);
    }
    *(bf16x8*)(w2h + base) = vh;
    *(bf16x8*)(w2l + base) = vl;
  }

  const int x0 = blockIdx.x * XPB;

  for (int xi = 0; xi < XPB; ++xi){
    const int x = x0 + xi;
    __syncthreads();   // iter0: gathers visible; later: WAR on coefT/outp

    // ---- load A rows, leaky_relu (f32), split to bf16 hi+lo ----
    bf16x8 ah[2][4], al[2][4];
    #pragma unroll
    for (int rt = 0; rt < 2; ++rt)
      #pragma unroll
      for (int kk = 0; kk < 4; ++kk){
        f32x8 v = *(const f32x8*)(xy + (((size_t)x * 256 + w * 32 + rt * 16 + lc) << 7)
                                     + kk * 32 + (lg << 3));
        bf16x8 vh, vl;
        #pragma unroll
        for (int j = 0; j < 8; ++j){
          float f = v[j];
          f = (f >= 0.f) ? f : 0.01f * f;      // leaky_relu, f32-exact
          uint16_t hi = f2bf(f);
          float    r  = f - bf2f(hi);
          vh[j] = (short)hi;
          vl[j] = (short)f2bf(r);
        }
        ah[rt][kk] = vh;
        al[rt][kk] = vl;
      }

    // ---- logits: lr @ W2, 3-pass split (padded to 16 cols) ----
    f32x4 la0 = {0.f,0.f,0.f,0.f}, la1 = {0.f,0.f,0.f,0.f};
    #pragma unroll
    for (int kk = 0; kk < 4; ++kk){
      bf16x8 wbh = *(const bf16x8*)(w2h + (kk * 64 + l) * 8);
      bf16x8 wbl = *(const bf16x8*)(w2l + (kk * 64 + l) * 8);
      la0 = mfma16(ah[0][kk], wbh, la0);
      la0 = mfma16(al[0][kk], wbh, la0);
      la0 = mfma16(ah[0][kk], wbl, la0);
      la1 = mfma16(ah[1][kk], wbh, la1);
      la1 = mfma16(al[1][kk], wbh, la1);
      la1 = mfma16(ah[1][kk], wbl, la1);
    }
    if (lc < 8){
      float b2v = ldsB2[lc];
      #pragma unroll
      for (int r = 0; r < 4; ++r){
        int row = (w << 5) + (lg << 2) + r;   // C/D: row=(l>>4)*4+r, col=l&15 (head)
        coefT[lc * 256 + row]      = la0[r] + b2v;
        coefT[lc * 256 + row + 16] = la1[r] + b2v;
      }
    }
    __syncthreads();   // logits visible

    // ---- softmax over Y for head w (mask-fill logits with 0 per reference) ----
    {
      float lgv[4];
      #pragma unroll
      for (int k = 0; k < 4; ++k){
        int y = (k << 6) + l;
        int mk = mask[(x << 8) + y];
        float v = coefT[w * 256 + y];
        lgv[k] = mk ? 0.f : v;
      }
      float mx = fmaxf(fmaxf(lgv[0], lgv[1]), fmaxf(lgv[2], lgv[3]));
      #pragma unroll
      for (int mm = 1; mm < 64; mm <<= 1) mx = fmaxf(mx, __shfl_xor(mx, mm));
      float e[4]; float sum = 0.f;
      #pragma unroll
      for (int k = 0; k < 4; ++k){ e[k] = __expf(lgv[k] - mx); sum += e[k]; }
      #pragma unroll
      for (int mm = 1; mm < 64; mm <<= 1) sum += __shfl_xor(sum, mm);
      float inv = 1.f / sum;
      #pragma unroll
      for (int k = 0; k < 4; ++k) coefT[w * 256 + (k << 6) + l] = e[k] * inv;
    }
    __syncthreads();   // coefs visible

    // ---- main GEMM 2-pass: acc[rt][nt], rows w*32+rt*16+lg*4+r, col nt*16+lc ----
    f32x4 acc[2][16];
    #pragma unroll
    for (int rt = 0; rt < 2; ++rt)
      #pragma unroll
      for (int nt = 0; nt < 16; ++nt)
        acc[rt][nt] = (f32x4){0.f,0.f,0.f,0.f};

    #pragma unroll
    for (int nt = 0; nt < 16; ++nt){
      #pragma unroll
      for (int kk = 0; kk < 4; ++kk){
        bf16x8 b = *(const bf16x8*)(w1h + ((nt * 4 + kk) * 64 + l) * 8);
        acc[0][nt] = mfma16(ah[0][kk], b, acc[0][nt]);
        acc[0][nt] = mfma16(al[0][kk], b, acc[0][nt]);
        acc[1][nt] = mfma16(ah[1][kk], b, acc[1][nt]);
        acc[1][nt] = mfma16(al[1][kk], b, acc[1][nt]);
      }
    }

    // ---- += b1, LN stats (butterfly over lc bits: 1,2,4,8) ----
    float s[2][4], q[2][4];
    #pragma unroll
    for (int rt = 0; rt < 2; ++rt)
      #pragma unroll
      for (int r = 0; r < 4; ++r){ s[rt][r] = 0.f; q[rt][r] = 0.f; }
    #pragma unroll
    for (int nt = 0; nt < 16; ++nt){
      float bv = ldsB1[nt * 16 + lc];
      #pragma unroll
      for (int rt = 0; rt < 2; ++rt)
        #pragma unroll
        for (int r = 0; r < 4; ++r){
          float v = acc[rt][nt][r] + bv;
          acc[rt][nt][r] = v;
          s[rt][r] += v;
          q[rt][r] += v * v;
        }
    }
    #pragma unroll
    for (int mm = 1; mm <= 8; mm <<= 1){
      #pragma unroll
      for (int rt = 0; rt < 2; ++rt)
        #pragma unroll
        for (int r = 0; r < 4; ++r){
          s[rt][r] += __shfl_xor(s[rt][r], mm);
          q[rt][r] += __shfl_xor(q[rt][r], mm);
        }
    }
    float mu[2][4], rstd[2][4];
    #pragma unroll
    for (int rt = 0; rt < 2; ++rt)
      #pragma unroll
      for (int r = 0; r < 4; ++r){
        float m = s[rt][r] * (1.f / 256.f);
        float var = q[rt][r] * (1.f / 256.f) - m * m;
        mu[rt][r] = m;
        rstd[rt][r] = rsqrtf(fmaxf(var, 0.f) + 1e-5f);
      }

    // ---- fused LN-affine + coef-weighted sum over this wave's 32 rows ----
    #pragma unroll
    for (int h = 0; h < 8; ++h){
      f32x4 c0 = *(const f32x4*)(coefT + h * 256 + (w << 5) + (lg << 2));
      f32x4 c1 = *(const f32x4*)(coefT + h * 256 + (w << 5) + 16 + (lg << 2));
      #pragma unroll
      for (int t = 0; t < 2; ++t){
        int nt = h * 2 + t;              // cols nt*16+lc belong to head nt>>1 == h
        int col = nt * 16 + lc;
        float gm = ldsG[col], bt = ldsBt[col];
        float p = 0.f;
        #pragma unroll
        for (int r = 0; r < 4; ++r){
          float hn0 = (acc[0][nt][r] - mu[0][r]) * rstd[0][r] * gm + bt;
          float hn1 = (acc[1][nt][r] - mu[1][r]) * rstd[1][r] * gm + bt;
          p += c0[r] * hn0 + c1[r] * hn1;
        }
        p += __shfl_xor(p, 16);
        p += __shfl_xor(p, 32);
        if (lg == 0) outp[w * 256 + col] = p;
      }
    }
    __syncthreads();   // outp partials visible

    // ---- cross-wave reduce + f32 store ----
    if (tid < 256){
      float sum = 0.f;
      #pragma unroll
      for (int ww = 0; ww < 8; ++ww) sum += outp[ww * 256 + tid];
      out[((size_t)x << 8) + tid] = sum;
    }
  }
}

extern "C" void kernel_launch(void* const* d_in, const int* in_sizes, int n_in,
                              void* d_out, int out_size, void* d_ws, size_t ws_size,
                              hipStream_t stream){
  (void)in_sizes; (void)n_in; (void)out_size; (void)d_ws; (void)ws_size;
  const float* xy    = (const float*)d_in[0];
  const int*   mask  = (const int*)d_in[1];
  const float* W1    = (const float*)d_in[2];
  const float* b1    = (const float*)d_in[3];
  const float* gamma = (const float*)d_in[4];
  const float* beta  = (const float*)d_in[5];
  const float* W2    = (const float*)d_in[6];
  const float* b2    = (const float*)d_in[7];

  hipFuncSetAttribute((const void*)attn_main,
                      hipFuncAttributeMaxDynamicSharedMemorySize, (int)LDS_BYTES);
  attn_main<<<NBLK, 512, LDS_BYTES, stream>>>(xy, mask, W1, b1, gamma, beta, W2, b2,
                                              (float*)d_out);
}